// Round 4
// baseline (420.727 us; speedup 1.0000x reference)
//
#include <hip/hip_runtime.h>
#include <stdint.h>

#define NUM_CLASSES 21
// ws layout: [0..20]=t_cnt, [21..41]=p_cnt, [42..62]=inter
#define WS_INTS (3 * NUM_CLASSES)

typedef float f32x4 __attribute__((ext_vector_type(4)));

__global__ void zero_ws_kernel(unsigned int* ws) {
    int i = threadIdx.x;
    if (i < WS_INTS) ws[i] = 0u;
}

// Argmax of 4 consecutive pixels packed in 21 f32x4 registers.
// Strict > scan == jnp.argmax first-max tie semantics.
__device__ __forceinline__ void argmax4(const f32x4* __restrict__ v, int* __restrict__ out_idx) {
    float best[4];
    int   idx[4];
#pragma unroll
    for (int p = 0; p < 4; ++p) { best[p] = -__builtin_inff(); idx[p] = 0; }
#pragma unroll
    for (int q = 0; q < NUM_CLASSES; ++q) {
        float vals[4] = {v[q][0], v[q][1], v[q][2], v[q][3]};
#pragma unroll
        for (int e = 0; e < 4; ++e) {
            int f = 4 * q + e;           // compile-time after unroll
            int p = f / NUM_CLASSES;
            int c = f % NUM_CLASSES;
            if (vals[e] > best[p]) { best[p] = vals[e]; idx[p] = c; }
        }
    }
#pragma unroll
    for (int p = 0; p < 4; ++p) out_idx[p] = idx[p];
}

// __launch_bounds__(256, 8): 8 waves/SIMD min -> compiler keeps VGPR <= 64
// (current build uses 52, fits). With grid = 8 blocks/CU this doubles resident
// waves 16 -> 32 per CU vs round 0. Theory: HBM fetch rate (~1.5 TB/s) is
// limited by per-CU in-flight misses, which scale with actively-issuing waves.
__global__ __launch_bounds__(256, 8) void hist_kernel(const float* __restrict__ yt,
                                                      const float* __restrict__ yp,
                                                      unsigned int* __restrict__ ws,
                                                      long long npix) {
    __shared__ unsigned int h[WS_INTS];
    for (int i = threadIdx.x; i < WS_INTS; i += 256) h[i] = 0u;
    __syncthreads();

    const long long ngroups = npix >> 2;                 // 4-pixel groups
    const long long tail = npix - ngroups * 4;
    const long long nthreads_needed = ngroups + (tail ? 1 : 0);
    const long long stride = (long long)gridDim.x * 256;

    for (long long g = (long long)blockIdx.x * 256 + threadIdx.x;
         g < nthreads_needed; g += stride) {
        if (g < ngroups) {
            const f32x4* t4 = (const f32x4*)yt + g * NUM_CLASSES;  // 21 x 16B = 4 pixels
            const f32x4* p4 = (const f32x4*)yp + g * NUM_CLASSES;

            // ---- T phase: issue ALL 21 loads before any compare (deep vmcnt queue)
            f32x4 vt[NUM_CLASSES];
#pragma unroll
            for (int q = 0; q < NUM_CLASSES; ++q) vt[q] = t4[q];
            __builtin_amdgcn_sched_barrier(0);
            int ti[4];
            argmax4(vt, ti);

            // ---- P phase
            f32x4 vp[NUM_CLASSES];
#pragma unroll
            for (int q = 0; q < NUM_CLASSES; ++q) vp[q] = p4[q];
            __builtin_amdgcn_sched_barrier(0);
            int pi[4];
            argmax4(vp, pi);

#pragma unroll
            for (int p = 0; p < 4; ++p) {
                atomicAdd(&h[ti[p]], 1u);
                atomicAdd(&h[NUM_CLASSES + pi[p]], 1u);
                if (ti[p] == pi[p]) atomicAdd(&h[2 * NUM_CLASSES + ti[p]], 1u);
            }
        } else {
            // scalar tail (npix % 4 != 0) — not taken for 8*512*512
            for (long long pix = ngroups * 4; pix < npix; ++pix) {
                const float* t = yt + pix * NUM_CLASSES;
                const float* p = yp + pix * NUM_CLASSES;
                float tb = t[0], pb = p[0];
                int tii = 0, pii = 0;
                for (int c = 1; c < NUM_CLASSES; ++c) {
                    if (t[c] > tb) { tb = t[c]; tii = c; }
                    if (p[c] > pb) { pb = p[c]; pii = c; }
                }
                atomicAdd(&h[tii], 1u);
                atomicAdd(&h[NUM_CLASSES + pii], 1u);
                if (tii == pii) atomicAdd(&h[2 * NUM_CLASSES + tii], 1u);
            }
        }
    }

    __syncthreads();
    for (int i = threadIdx.x; i < WS_INTS; i += 256) {
        if (h[i]) atomicAdd(&ws[i], h[i]);
    }
}

__global__ void finalize_kernel(const unsigned int* __restrict__ ws,
                                float* __restrict__ out) {
    int c = threadIdx.x;  // one wave
    float iou = 0.0f, valid = 0.0f;
    if (c < NUM_CLASSES) {
        float inter = (float)ws[2 * NUM_CLASSES + c];
        float uni   = (float)ws[c] + (float)ws[NUM_CLASSES + c] - inter;
        if (uni > 0.0f) { iou = inter / uni; valid = 1.0f; }
    }
#pragma unroll
    for (int off = 32; off > 0; off >>= 1) {
        iou   += __shfl_down(iou, off);
        valid += __shfl_down(valid, off);
    }
    if (c == 0) out[0] = iou / valid;
}

extern "C" void kernel_launch(void* const* d_in, const int* in_sizes, int n_in,
                              void* d_out, int out_size, void* d_ws, size_t ws_size,
                              hipStream_t stream) {
    const float* y_true = (const float*)d_in[0];
    const float* y_pred = (const float*)d_in[1];
    float* out = (float*)d_out;
    unsigned int* ws = (unsigned int*)d_ws;

    long long total = (long long)in_sizes[0];   // 44,040,192
    long long npix = total / NUM_CLASSES;       // 2,097,152

    int block = 256;
    int grid = 2048;   // 8 blocks/CU co-resident (52 VGPR -> 8 waves/SIMD fits);
                       // 1 grid-stride iter/thread for 524288 groups

    zero_ws_kernel<<<1, 64, 0, stream>>>(ws);
    hist_kernel<<<grid, block, 0, stream>>>(y_true, y_pred, ws, npix);
    finalize_kernel<<<1, 64, 0, stream>>>(ws, out);
}

// Round 5
// 349.588 us; speedup vs baseline: 1.2035x; 1.2035x over previous
//
#include <hip/hip_runtime.h>
#include <stdint.h>

#define NUM_CLASSES 21
// ws layout: [0..20]=t_cnt, [21..41]=p_cnt, [42..62]=inter
#define WS_INTS (3 * NUM_CLASSES)

typedef float f32x4 __attribute__((ext_vector_type(4)));

__global__ void zero_ws_kernel(unsigned int* ws) {
    int i = threadIdx.x;
    if (i < WS_INTS) ws[i] = 0u;
}

// Argmax of 4 consecutive pixels packed in 21 f32x4 registers.
// Strict > scan == jnp.argmax first-max tie semantics.
__device__ __forceinline__ void argmax4(const f32x4* __restrict__ v, int* __restrict__ out_idx) {
    float best[4];
    int   idx[4];
#pragma unroll
    for (int p = 0; p < 4; ++p) { best[p] = -__builtin_inff(); idx[p] = 0; }
#pragma unroll
    for (int q = 0; q < NUM_CLASSES; ++q) {
        float vals[4] = {v[q][0], v[q][1], v[q][2], v[q][3]};
#pragma unroll
        for (int e = 0; e < 4; ++e) {
            int f = 4 * q + e;           // compile-time after unroll
            int p = f / NUM_CLASSES;
            int c = f % NUM_CLASSES;
            if (vals[e] > best[p]) { best[p] = vals[e]; idx[p] = c; }
        }
    }
#pragma unroll
    for (int p = 0; p < 4; ++p) out_idx[p] = idx[p];
}

// NOTE: __launch_bounds__ 2nd arg kept at 4 ON PURPOSE — it is only the
// compiler's register budget (4 waves/EU -> <=128 VGPR -> allocator picks 52,
// no spills). Runtime occupancy is resource-determined: at 52 VGPR and 512 B
// LDS, 8 blocks/CU fit. Round 4 proved (256,8) forces VGPR=32 -> 284 MB of
// scratch spill traffic. Occupancy is raised via grid=2048 instead.
__global__ __launch_bounds__(256, 4) void hist_kernel(const float* __restrict__ yt,
                                                      const float* __restrict__ yp,
                                                      unsigned int* __restrict__ ws,
                                                      long long npix) {
    __shared__ unsigned int h[WS_INTS];
    for (int i = threadIdx.x; i < WS_INTS; i += 256) h[i] = 0u;
    __syncthreads();

    const long long ngroups = npix >> 2;                 // 4-pixel groups
    const long long tail = npix - ngroups * 4;
    const long long nthreads_needed = ngroups + (tail ? 1 : 0);
    const long long stride = (long long)gridDim.x * 256;

    for (long long g = (long long)blockIdx.x * 256 + threadIdx.x;
         g < nthreads_needed; g += stride) {
        if (g < ngroups) {
            const f32x4* t4 = (const f32x4*)yt + g * NUM_CLASSES;  // 21 x 16B = 4 pixels
            const f32x4* p4 = (const f32x4*)yp + g * NUM_CLASSES;

            // ---- T phase: issue ALL 21 loads before any compare (deep vmcnt queue)
            f32x4 vt[NUM_CLASSES];
#pragma unroll
            for (int q = 0; q < NUM_CLASSES; ++q) vt[q] = t4[q];
            __builtin_amdgcn_sched_barrier(0);
            int ti[4];
            argmax4(vt, ti);

            // ---- P phase
            f32x4 vp[NUM_CLASSES];
#pragma unroll
            for (int q = 0; q < NUM_CLASSES; ++q) vp[q] = p4[q];
            __builtin_amdgcn_sched_barrier(0);
            int pi[4];
            argmax4(vp, pi);

#pragma unroll
            for (int p = 0; p < 4; ++p) {
                atomicAdd(&h[ti[p]], 1u);
                atomicAdd(&h[NUM_CLASSES + pi[p]], 1u);
                if (ti[p] == pi[p]) atomicAdd(&h[2 * NUM_CLASSES + ti[p]], 1u);
            }
        } else {
            // scalar tail (npix % 4 != 0) — not taken for 8*512*512
            for (long long pix = ngroups * 4; pix < npix; ++pix) {
                const float* t = yt + pix * NUM_CLASSES;
                const float* p = yp + pix * NUM_CLASSES;
                float tb = t[0], pb = p[0];
                int tii = 0, pii = 0;
                for (int c = 1; c < NUM_CLASSES; ++c) {
                    if (t[c] > tb) { tb = t[c]; tii = c; }
                    if (p[c] > pb) { pb = p[c]; pii = c; }
                }
                atomicAdd(&h[tii], 1u);
                atomicAdd(&h[NUM_CLASSES + pii], 1u);
                if (tii == pii) atomicAdd(&h[2 * NUM_CLASSES + tii], 1u);
            }
        }
    }

    __syncthreads();
    for (int i = threadIdx.x; i < WS_INTS; i += 256) {
        if (h[i]) atomicAdd(&ws[i], h[i]);
    }
}

__global__ void finalize_kernel(const unsigned int* __restrict__ ws,
                                float* __restrict__ out) {
    int c = threadIdx.x;  // one wave
    float iou = 0.0f, valid = 0.0f;
    if (c < NUM_CLASSES) {
        float inter = (float)ws[2 * NUM_CLASSES + c];
        float uni   = (float)ws[c] + (float)ws[NUM_CLASSES + c] - inter;
        if (uni > 0.0f) { iou = inter / uni; valid = 1.0f; }
    }
#pragma unroll
    for (int off = 32; off > 0; off >>= 1) {
        iou   += __shfl_down(iou, off);
        valid += __shfl_down(valid, off);
    }
    if (c == 0) out[0] = iou / valid;
}

extern "C" void kernel_launch(void* const* d_in, const int* in_sizes, int n_in,
                              void* d_out, int out_size, void* d_ws, size_t ws_size,
                              hipStream_t stream) {
    const float* y_true = (const float*)d_in[0];
    const float* y_pred = (const float*)d_in[1];
    float* out = (float*)d_out;
    unsigned int* ws = (unsigned int*)d_ws;

    long long total = (long long)in_sizes[0];   // 44,040,192
    long long npix = total / NUM_CLASSES;       // 2,097,152

    int block = 256;
    int grid = 2048;   // 8 blocks/CU co-resident at 52 VGPR (512/52 -> 8 waves/SIMD);
                       // 524288 groups = exactly 1 per thread

    zero_ws_kernel<<<1, 64, 0, stream>>>(ws);
    hist_kernel<<<grid, block, 0, stream>>>(y_true, y_pred, ws, npix);
    finalize_kernel<<<1, 64, 0, stream>>>(ws, out);
}